// Round 1
// baseline (430.707 us; speedup 1.0000x reference)
//
#include <hip/hip_runtime.h>
#include <hip/hip_bf16.h>
#include <stdint.h>

// ---------- types ----------
typedef __attribute__((ext_vector_type(8))) short bf16x8;
typedef __attribute__((ext_vector_type(4))) short short4v;
typedef __attribute__((ext_vector_type(4))) float f32x4;

#define DEV static __device__ __forceinline__

DEV float bf2f(short u) {
    union { float f; uint32_t i; } c; c.i = ((uint32_t)(uint16_t)u) << 16; return c.f;
}
DEV short f2bf(float f) {
    union { float f; uint32_t i; } c; c.f = f;
    uint32_t i = c.i;
    uint32_t r = i + 0x7FFFu + ((i >> 16) & 1u);   // RNE
    return (short)(r >> 16);
}

DEV void gload_lds16(const short* g, short* l) {
    __builtin_amdgcn_global_load_lds(
        (const __attribute__((address_space(1))) void*)g,
        (__attribute__((address_space(3))) void*)l,
        16, 0, 0);
}

// ---------- fp32 -> bf16 convert (exact-size launch, 8 elems/thread) ----------
__global__ __launch_bounds__(256)
void cvt_f32_bf16(const float* __restrict__ in, short* __restrict__ out) {
    long i = ((long)blockIdx.x * 256 + threadIdx.x) * 8;
    float4 a = *(const float4*)&in[i];
    float4 b = *(const float4*)&in[i + 4];
    bf16x8 o;
    o[0] = f2bf(a.x); o[1] = f2bf(a.y); o[2] = f2bf(a.z); o[3] = f2bf(a.w);
    o[4] = f2bf(b.x); o[5] = f2bf(b.y); o[6] = f2bf(b.z); o[7] = f2bf(b.w);
    *(bf16x8*)&out[i] = o;
}

// ---------- W [H][D] fp32  ->  Wt [D][H] bf16 ----------
__global__ __launch_bounds__(256)
void transpose_w(const float* __restrict__ W, short* __restrict__ Wt) {
    const int HD = 1024;
    __shared__ float tile[32][33];
    int bx = blockIdx.x, by = blockIdx.y;
    int tx = threadIdx.x & 31, ty = threadIdx.x >> 5;  // 32 x 8
    #pragma unroll
    for (int r = ty; r < 32; r += 8)
        tile[r][tx] = W[(long)(by * 32 + r) * HD + bx * 32 + tx];
    __syncthreads();
    #pragma unroll
    for (int r = ty; r < 32; r += 8)
        Wt[(long)(bx * 32 + r) * HD + by * 32 + tx] = f2bf(tile[tx][r]);
}

// ---------- NT GEMM: C[M][N] = A[M][K] * Bt[N][K]^T  (bf16 in, fp32 acc) ----------
// EPI: 0 = bf16 row-major out
//      1 = bf16 transposed out -> Vt[b][n][t]  (T=2048 hardcoded)
//      2 = score: *scale, band mask (keep i-j<=256 && j-i<=255), bf16 out; zero-tiles skipped
//      3 = fp32 row-major out
#define BM 128
#define BN 128
#define BK 32
#define NTHREADS 256

template<int EPI>
__global__ __launch_bounds__(256)
void gemm_nt(const short* __restrict__ A, const short* __restrict__ Bt,
             void* __restrict__ Cv, int M, int N, int K,
             long sAz, long sBz, long sCz, float scale)
{
    __shared__ __align__(16) short lsA[BM * BK];
    __shared__ __align__(16) short lsB[BN * BK];

    const int bz = blockIdx.z;
    A  += (long)bz * sAz;
    Bt += (long)bz * sBz;

    const int m0 = blockIdx.y * BM;
    const int n0 = blockIdx.x * BN;

    const int tid  = threadIdx.x;
    const int lane = tid & 63;
    const int w    = tid >> 6;
    const int wm   = (w >> 1) * 64;
    const int wn   = (w & 1) * 64;

    if (EPI == 2) {
        // tile fully outside band: write zeros, skip all compute
        if (n0 + BN - 1 < m0 - 256 || n0 > m0 + BM - 1 + 255) {
            short* C = (short*)Cv + (long)bz * sCz;
            #pragma unroll
            for (int it = 0; it < 8; ++it) {
                int e = (it * NTHREADS + tid) * 8;     // elem offset in 128x128 tile
                int rr = e >> 7, cc = e & 127;
                int4 z; z.x = z.y = z.z = z.w = 0;
                *(int4*)&C[(long)(m0 + rr) * N + n0 + cc] = z;
            }
            return;
        }
    }

    f32x4 acc[4][4];
    #pragma unroll
    for (int i = 0; i < 4; ++i)
        #pragma unroll
        for (int j = 0; j < 4; ++j) { acc[i][j][0]=0.f; acc[i][j][1]=0.f; acc[i][j][2]=0.f; acc[i][j][3]=0.f; }

    for (int k0 = 0; k0 < K; k0 += BK) {
        // stage 128x32 A-tile and 128x32 B-tile (row-major [128][32] bf16)
        #pragma unroll
        for (int c = 0; c < 2; ++c) {
            int sbase = c * NTHREADS + w * 64;       // wave-uniform slot base
            int s = sbase + lane;                    // per-lane slot (16B each)
            int row = s >> 2, kg = s & 3;
            gload_lds16(A  + (long)(m0 + row) * K + k0 + kg * 8, &lsA[sbase * 8]);
            gload_lds16(Bt + (long)(n0 + row) * K + k0 + kg * 8, &lsB[sbase * 8]);
        }
        __syncthreads();

        bf16x8 fa[4], fb[4];
        #pragma unroll
        for (int mi = 0; mi < 4; ++mi)
            fa[mi] = *(const bf16x8*)&lsA[(wm + mi * 16 + (lane & 15)) * BK + (lane >> 4) * 8];
        #pragma unroll
        for (int ni = 0; ni < 4; ++ni)
            fb[ni] = *(const bf16x8*)&lsB[(wn + ni * 16 + (lane & 15)) * BK + (lane >> 4) * 8];
        #pragma unroll
        for (int mi = 0; mi < 4; ++mi)
            #pragma unroll
            for (int ni = 0; ni < 4; ++ni)
                acc[mi][ni] = __builtin_amdgcn_mfma_f32_16x16x32_bf16(fa[mi], fb[ni], acc[mi][ni], 0, 0, 0);
        __syncthreads();
    }

    const int fr = lane & 15;    // n within fragment
    const int fq = lane >> 4;    // row-group: C row = fq*4 + r

    if (EPI == 0) {
        short* C = (short*)Cv + (long)bz * sCz;
        #pragma unroll
        for (int mi = 0; mi < 4; ++mi)
            #pragma unroll
            for (int ni = 0; ni < 4; ++ni)
                #pragma unroll
                for (int r = 0; r < 4; ++r) {
                    int row = m0 + wm + mi * 16 + fq * 4 + r;
                    int col = n0 + wn + ni * 16 + fr;
                    C[(long)row * N + col] = f2bf(acc[mi][ni][r]);
                }
    } else if (EPI == 1) {
        // Vt[b][col][t], t = row % 2048, 4 consecutive t per lane -> 8B store
        short* C = (short*)Cv;
        #pragma unroll
        for (int mi = 0; mi < 4; ++mi)
            #pragma unroll
            for (int ni = 0; ni < 4; ++ni) {
                int col  = n0 + wn + ni * 16 + fr;
                int row0 = m0 + wm + mi * 16 + fq * 4;
                int b = row0 >> 11;
                int t = row0 & 2047;
                short4v v;
                #pragma unroll
                for (int r = 0; r < 4; ++r) v[r] = f2bf(acc[mi][ni][r]);
                *(short4v*)&C[((long)b * N + col) * 2048 + t] = v;
            }
    } else if (EPI == 2) {
        short* C = (short*)Cv + (long)bz * sCz;
        #pragma unroll
        for (int mi = 0; mi < 4; ++mi)
            #pragma unroll
            for (int ni = 0; ni < 4; ++ni)
                #pragma unroll
                for (int r = 0; r < 4; ++r) {
                    int i = m0 + wm + mi * 16 + fq * 4 + r;
                    int j = n0 + wn + ni * 16 + fr;
                    bool keep = (i - j <= 256) && (j - i <= 255);
                    float s = keep ? acc[mi][ni][r] * scale : 0.f;
                    C[(long)i * N + j] = f2bf(s);
                }
    } else {
        float* C = (float*)Cv + (long)bz * sCz;
        #pragma unroll
        for (int mi = 0; mi < 4; ++mi)
            #pragma unroll
            for (int ni = 0; ni < 4; ++ni)
                #pragma unroll
                for (int r = 0; r < 4; ++r) {
                    int row = m0 + wm + mi * 16 + fq * 4 + r;
                    int col = n0 + wn + ni * 16 + fr;
                    C[(long)row * N + col] = acc[mi][ni][r];
                }
    }
}

// ---------- in-place row softmax over bf16 [rows][2048] ----------
__global__ __launch_bounds__(256)
void softmax_rows(short* __restrict__ S) {
    const int T = 2048;
    long base = (long)blockIdx.x * T;
    int tid = threadIdx.x;
    bf16x8 v = *(const bf16x8*)&S[base + tid * 8];
    float f[8];
    float mx = -1e30f;
    #pragma unroll
    for (int j = 0; j < 8; ++j) { f[j] = bf2f(v[j]); mx = fmaxf(mx, f[j]); }
    #pragma unroll
    for (int o = 32; o; o >>= 1) mx = fmaxf(mx, __shfl_xor(mx, o));
    __shared__ float redm[4], reds[4];
    int w = tid >> 6;
    if ((tid & 63) == 0) redm[w] = mx;
    __syncthreads();
    mx = fmaxf(fmaxf(redm[0], redm[1]), fmaxf(redm[2], redm[3]));
    float sum = 0.f;
    #pragma unroll
    for (int j = 0; j < 8; ++j) { f[j] = __expf(f[j] - mx); sum += f[j]; }
    #pragma unroll
    for (int o = 32; o; o >>= 1) sum += __shfl_xor(sum, o);
    if ((tid & 63) == 0) reds[w] = sum;
    __syncthreads();
    sum = reds[0] + reds[1] + reds[2] + reds[3];
    float inv = 1.f / sum;
    #pragma unroll
    for (int j = 0; j < 8; ++j) v[j] = f2bf(f[j] * inv);
    *(bf16x8*)&S[base + tid * 8] = v;
}

// ---------- launch ----------
extern "C" void kernel_launch(void* const* d_in, const int* in_sizes, int n_in,
                              void* d_out, int out_size, void* d_ws, size_t ws_size,
                              hipStream_t stream) {
    const int B = 8, T = 2048, H = 1024, D = 1024;
    const long MT = (long)B * T;  // 16384

    const float* X  = (const float*)d_in[0];
    const float* WQ = (const float*)d_in[1];
    const float* WK = (const float*)d_in[2];
    const float* WV = (const float*)d_in[3];
    float* out = (float*)d_out;

    char* ws = (char*)d_ws;
    size_t off = 0;
    auto alloc = [&](size_t bytes) {
        char* p = ws + off;
        off += (bytes + 255) & ~(size_t)255;
        return p;
    };
    short* Xb = (short*)alloc(MT * H * 2);          // 33.5 MB
    short* Wt = (short*)alloc(3L * D * H * 2);      //  6.3 MB  (Q,K,V transposed weights)
    short* Qb = (short*)alloc(MT * D * 2);          // 33.5 MB
    short* Kb = (short*)alloc(MT * D * 2);          // 33.5 MB
    short* Vt = (short*)alloc((long)B * D * T * 2); // 33.5 MB  [b][d][t]
    short* S  = (short*)alloc((long)B * T * T * 2); // 67.1 MB  scores -> attn in place
    if (off > ws_size) return;   // workspace too small: fail cleanly

    // 1) bf16 conversions
    cvt_f32_bf16<<<(int)(MT * H / 2048), 256, 0, stream>>>(X, Xb);
    transpose_w<<<dim3(32, 32), 256, 0, stream>>>(WQ, Wt);
    transpose_w<<<dim3(32, 32), 256, 0, stream>>>(WK, Wt + (long)D * H);
    transpose_w<<<dim3(32, 32), 256, 0, stream>>>(WV, Wt + 2L * D * H);

    // 2) projections: Q, K (row-major), V written transposed per batch
    dim3 gProj(D / BN, MT / BM, 1);
    gemm_nt<0><<<gProj, 256, 0, stream>>>(Xb, Wt,                Qb, (int)MT, D, H, 0, 0, 0, 1.f);
    gemm_nt<0><<<gProj, 256, 0, stream>>>(Xb, Wt + (long)D * H,  Kb, (int)MT, D, H, 0, 0, 0, 1.f);
    gemm_nt<1><<<gProj, 256, 0, stream>>>(Xb, Wt + 2L * D * H,   Vt, (int)MT, D, H, 0, 0, 0, 1.f);

    // 3) scores: S = (Q K^T)/32, band-masked to 0 outside, bf16
    gemm_nt<2><<<dim3(T / BN, T / BM, B), 256, 0, stream>>>(
        Qb, Kb, S, T, T, D, (long)T * D, (long)T * D, (long)T * T, 1.f / 32.f);

    // 4) full-row softmax in place (masked zeros participate, matching reference)
    softmax_rows<<<(int)MT, 256, 0, stream>>>(S);

    // 5) dense PV: out[b] = attn[b] @ V[b]   (A = attn bf16, Bt = Vt)
    gemm_nt<3><<<dim3(D / BN, T / BM, B), 256, 0, stream>>>(
        S, Vt, out, T, D, T, (long)T * T, (long)D * T, (long)T * D, 1.f);
}

// Round 2
// 338.177 us; speedup vs baseline: 1.2736x; 1.2736x over previous
//
#include <hip/hip_runtime.h>
#include <hip/hip_bf16.h>
#include <stdint.h>

// ---------- types ----------
typedef __attribute__((ext_vector_type(8))) short bf16x8;
typedef __attribute__((ext_vector_type(4))) short short4v;
typedef __attribute__((ext_vector_type(4))) float f32x4;

#define DEV static __device__ __forceinline__

DEV float bf2f(short u) {
    union { float f; uint32_t i; } c; c.i = ((uint32_t)(uint16_t)u) << 16; return c.f;
}
DEV short f2bf(float f) {
    union { float f; uint32_t i; } c; c.f = f;
    uint32_t i = c.i;
    uint32_t r = i + 0x7FFFu + ((i >> 16) & 1u);   // RNE
    return (short)(r >> 16);
}

DEV void gload_lds16(const short* g, short* l) {
    __builtin_amdgcn_global_load_lds(
        (const __attribute__((address_space(1))) void*)g,
        (__attribute__((address_space(3))) void*)l,
        16, 0, 0);
}

// ---------- fp32 -> bf16 convert (8 elems/thread) ----------
__global__ __launch_bounds__(256)
void cvt_f32_bf16(const float* __restrict__ in, short* __restrict__ out) {
    long i = ((long)blockIdx.x * 256 + threadIdx.x) * 8;
    float4 a = *(const float4*)&in[i];
    float4 b = *(const float4*)&in[i + 4];
    bf16x8 o;
    o[0] = f2bf(a.x); o[1] = f2bf(a.y); o[2] = f2bf(a.z); o[3] = f2bf(a.w);
    o[4] = f2bf(b.x); o[5] = f2bf(b.y); o[6] = f2bf(b.z); o[7] = f2bf(b.w);
    *(bf16x8*)&out[i] = o;
}

// ---------- W [H][D] fp32  ->  Wt [D][H] bf16 ----------
__global__ __launch_bounds__(256)
void transpose_w(const float* __restrict__ W, short* __restrict__ Wt) {
    const int HD = 1024;
    __shared__ float tile[32][33];
    int bx = blockIdx.x, by = blockIdx.y;
    int tx = threadIdx.x & 31, ty = threadIdx.x >> 5;  // 32 x 8
    #pragma unroll
    for (int r = ty; r < 32; r += 8)
        tile[r][tx] = W[(long)(by * 32 + r) * HD + bx * 32 + tx];
    __syncthreads();
    #pragma unroll
    for (int r = ty; r < 32; r += 8)
        Wt[(long)(bx * 32 + r) * HD + by * 32 + tx] = f2bf(tile[tx][r]);
}

// ---------- shared 128x128x32 K-step (stage + MFMA) ----------
#define BM 128
#define BN 128
#define BK 32
#define NTHREADS 256

DEV void kstep128(const short* __restrict__ A, const short* __restrict__ Bt,
                  int ldA, int ldB, int m0, int n0, int k0,
                  short* lsA, short* lsB,
                  int lane, int w, int wm, int wn, f32x4 acc[4][4])
{
    #pragma unroll
    for (int c = 0; c < 2; ++c) {
        int sbase = c * NTHREADS + w * 64;       // wave-uniform slot base
        int s = sbase + lane;                    // per-lane slot (16B)
        int row = s >> 2, kg = s & 3;
        gload_lds16(A  + (long)(m0 + row) * ldA + k0 + kg * 8, &lsA[sbase * 8]);
        gload_lds16(Bt + (long)(n0 + row) * ldB + k0 + kg * 8, &lsB[sbase * 8]);
    }
    __syncthreads();
    bf16x8 fa[4], fb[4];
    #pragma unroll
    for (int mi = 0; mi < 4; ++mi)
        fa[mi] = *(const bf16x8*)&lsA[(wm + mi * 16 + (lane & 15)) * BK + (lane >> 4) * 8];
    #pragma unroll
    for (int ni = 0; ni < 4; ++ni)
        fb[ni] = *(const bf16x8*)&lsB[(wn + ni * 16 + (lane & 15)) * BK + (lane >> 4) * 8];
    #pragma unroll
    for (int mi = 0; mi < 4; ++mi)
        #pragma unroll
        for (int ni = 0; ni < 4; ++ni)
            acc[mi][ni] = __builtin_amdgcn_mfma_f32_16x16x32_bf16(fa[mi], fb[ni], acc[mi][ni], 0, 0, 0);
    __syncthreads();
}

#define ACC_INIT(acc)                                                          \
    _Pragma("unroll") for (int i = 0; i < 4; ++i)                              \
    _Pragma("unroll") for (int j = 0; j < 4; ++j) {                            \
        acc[i][j][0]=0.f; acc[i][j][1]=0.f; acc[i][j][2]=0.f; acc[i][j][3]=0.f; }

// ---------- projections: C[M][N] = A[M][K] * Bt[N][K]^T ----------
// EPI: 0 = bf16 row-major; 1 = bf16 transposed -> Vt[b][n][t] (T=2048)
template<int EPI>
__global__ __launch_bounds__(256)
void gemm_nt(const short* __restrict__ A, const short* __restrict__ Bt,
             short* __restrict__ C, int M, int N, int K)
{
    __shared__ __align__(16) short lsA[BM * BK];
    __shared__ __align__(16) short lsB[BN * BK];
    const int m0 = blockIdx.y * BM, n0 = blockIdx.x * BN;
    const int tid = threadIdx.x, lane = tid & 63, w = tid >> 6;
    const int wm = (w >> 1) * 64, wn = (w & 1) * 64;

    f32x4 acc[4][4];
    ACC_INIT(acc);
    for (int k0 = 0; k0 < K; k0 += BK)
        kstep128(A, Bt, K, K, m0, n0, k0, lsA, lsB, lane, w, wm, wn, acc);

    const int fr = lane & 15, fq = lane >> 4;
    if (EPI == 0) {
        #pragma unroll
        for (int mi = 0; mi < 4; ++mi)
            #pragma unroll
            for (int ni = 0; ni < 4; ++ni)
                #pragma unroll
                for (int r = 0; r < 4; ++r) {
                    int row = m0 + wm + mi * 16 + fq * 4 + r;
                    int col = n0 + wn + ni * 16 + fr;
                    C[(long)row * N + col] = f2bf(acc[mi][ni][r]);
                }
    } else {
        // Vt[b][col][t], 4 consecutive t per lane -> 8B store
        #pragma unroll
        for (int mi = 0; mi < 4; ++mi)
            #pragma unroll
            for (int ni = 0; ni < 4; ++ni) {
                int col  = n0 + wn + ni * 16 + fr;
                int row0 = m0 + wm + mi * 16 + fq * 4;
                int b = row0 >> 11, t = row0 & 2047;
                short4v v;
                #pragma unroll
                for (int r = 0; r < 4; ++r) v[r] = f2bf(acc[mi][ni][r]);
                *(short4v*)&C[((long)b * N + col) * 2048 + t] = v;
            }
    }
}

// ---------- band scores: S[b][i][j] = (q.k)/32 masked, only 5 tiles/row-tile ----------
__global__ __launch_bounds__(256)
void gemm_scores(const short* __restrict__ Q, const short* __restrict__ K,
                 short* __restrict__ S, float scale)
{
    const int T = 2048, D = 1024;
    const int mb = blockIdx.y;
    const int kb = mb + (int)blockIdx.x - 2;
    if (kb < 0 || kb > 15) return;
    const int bz = blockIdx.z;
    const short* A  = Q + (long)bz * T * D;
    const short* Bt = K + (long)bz * T * D;
    short* C = S + (long)bz * T * T;

    __shared__ __align__(16) short lsA[BM * BK];
    __shared__ __align__(16) short lsB[BN * BK];
    const int m0 = mb * BM, n0 = kb * BN;
    const int tid = threadIdx.x, lane = tid & 63, w = tid >> 6;
    const int wm = (w >> 1) * 64, wn = (w & 1) * 64;

    f32x4 acc[4][4];
    ACC_INIT(acc);
    for (int k0 = 0; k0 < D; k0 += BK)
        kstep128(A, Bt, D, D, m0, n0, k0, lsA, lsB, lane, w, wm, wn, acc);

    const int fr = lane & 15, fq = lane >> 4;
    #pragma unroll
    for (int mi = 0; mi < 4; ++mi)
        #pragma unroll
        for (int ni = 0; ni < 4; ++ni)
            #pragma unroll
            for (int r = 0; r < 4; ++r) {
                int i = m0 + wm + mi * 16 + fq * 4 + r;
                int j = n0 + wn + ni * 16 + fr;
                bool keep = (i - j <= 256) && (j - i <= 255);
                float s = keep ? acc[mi][ni][r] * scale : 0.f;
                C[(long)i * T + j] = f2bf(s);
            }
}

// ---------- band softmax: in place P' = a - c; Crow[i] = c ----------
// Row i reads exactly the 5 tiles scores wrote: cols [max(mb-2,0)*128, min(mb+2,15)*128+128)
// In-tile masked entries are 0 -> weight c -> P' = 0 exactly.
__global__ __launch_bounds__(256)
void softmax_band(short* __restrict__ S, float* __restrict__ Crow) {
    const int T = 2048;
    int wid = (int)blockIdx.x * 4 + (threadIdx.x >> 6);
    int lane = threadIdx.x & 63;
    int b = wid >> 11, t = wid & 2047;
    int mb = t >> 7;
    int tlo = max(mb - 2, 0) * 128;
    int thi = min(mb + 2, 15) * 128 + 128;
    int nvec = (thi - tlo) >> 3;                   // 48..80
    short* row = S + ((long)b * T + t) * T + tlo;

    bool h0 = lane < nvec;
    bool h1 = lane + 64 < nvec;
    bf16x8 v0, v1;
    float f0[8], f1[8];
    float m = 0.f;                                  // masked zeros always exist
    if (h0) {
        v0 = *(const bf16x8*)&row[lane * 8];
        #pragma unroll
        for (int j = 0; j < 8; ++j) { f0[j] = bf2f(v0[j]); m = fmaxf(m, f0[j]); }
    }
    if (h1) {
        v1 = *(const bf16x8*)&row[(lane + 64) * 8];
        #pragma unroll
        for (int j = 0; j < 8; ++j) { f1[j] = bf2f(v1[j]); m = fmaxf(m, f1[j]); }
    }
    #pragma unroll
    for (int o = 32; o; o >>= 1) m = fmaxf(m, __shfl_xor(m, o));

    float e0[8], e1[8];
    float sum = 0.f;
    if (h0) {
        #pragma unroll
        for (int j = 0; j < 8; ++j) { e0[j] = __expf(f0[j] - m); sum += e0[j]; }
    }
    if (h1) {
        #pragma unroll
        for (int j = 0; j < 8; ++j) { e1[j] = __expf(f1[j] - m); sum += e1[j]; }
    }
    #pragma unroll
    for (int o = 32; o; o >>= 1) sum += __shfl_xor(sum, o);
    float em = __expf(-m);
    sum += (float)(2048 - nvec * 8) * em;
    float inv = 1.f / sum;
    float c = em * inv;

    if (h0) {
        #pragma unroll
        for (int j = 0; j < 8; ++j) v0[j] = f2bf(e0[j] * inv - c);
        *(bf16x8*)&row[lane * 8] = v0;
    }
    if (h1) {
        #pragma unroll
        for (int j = 0; j < 8; ++j) v1[j] = f2bf(e1[j] * inv - c);
        *(bf16x8*)&row[(lane + 64) * 8] = v1;
    }
    if (lane == 0) Crow[wid] = c;
}

// ---------- Vsum[b][d] = sum_t Vt[b][d][t] ----------
__global__ __launch_bounds__(256)
void vsum_rows(const short* __restrict__ Vt, float* __restrict__ Vsum) {
    int rowid = (int)blockIdx.x * 4 + (threadIdx.x >> 6);
    int lane = threadIdx.x & 63;
    const short* r = Vt + (long)rowid * 2048;
    float s = 0.f;
    #pragma unroll
    for (int v = 0; v < 4; ++v) {
        bf16x8 x = *(const bf16x8*)&r[(lane + v * 64) * 8];
        #pragma unroll
        for (int j = 0; j < 8; ++j) s += bf2f(x[j]);
    }
    #pragma unroll
    for (int o = 32; o; o >>= 1) s += __shfl_xor(s, o);
    if (lane == 0) Vsum[rowid] = s;
}

// ---------- band PV: out = P'_band @ V + c_i * Vsum ----------
__global__ __launch_bounds__(256)
void gemm_pv(const short* __restrict__ S, const short* __restrict__ Vt,
             const float* __restrict__ Crow, const float* __restrict__ Vsum,
             float* __restrict__ out)
{
    const int T = 2048, D = 1024;
    const int bz = blockIdx.z, mb = blockIdx.y;
    const short* A  = S  + (long)bz * T * T;   // ld T
    const short* Bt = Vt + (long)bz * D * T;   // ld T
    const int m0 = mb * BM, n0 = blockIdx.x * BN;

    __shared__ __align__(16) short lsA[BM * BK];
    __shared__ __align__(16) short lsB[BN * BK];
    const int tid = threadIdx.x, lane = tid & 63, w = tid >> 6;
    const int wm = (w >> 1) * 64, wn = (w & 1) * 64;

    const int klo = max(mb - 2, 0) * 128;
    const int khi = min(mb + 2, 15) * 128 + 128;

    f32x4 acc[4][4];
    ACC_INIT(acc);
    for (int k0 = klo; k0 < khi; k0 += BK)
        kstep128(A, Bt, T, T, m0, n0, k0, lsA, lsB, lane, w, wm, wn, acc);

    const int fr = lane & 15, fq = lane >> 4;
    #pragma unroll
    for (int mi = 0; mi < 4; ++mi)
        #pragma unroll
        for (int r = 0; r < 4; ++r) {
            int i = m0 + wm + mi * 16 + fq * 4 + r;
            float ci = Crow[bz * T + i];
            #pragma unroll
            for (int ni = 0; ni < 4; ++ni) {
                int col = n0 + wn + ni * 16 + fr;
                out[((long)bz * T + i) * D + col] = acc[mi][ni][r] + ci * Vsum[bz * D + col];
            }
        }
}

// ---------- launch ----------
extern "C" void kernel_launch(void* const* d_in, const int* in_sizes, int n_in,
                              void* d_out, int out_size, void* d_ws, size_t ws_size,
                              hipStream_t stream) {
    const int B = 8, T = 2048, H = 1024, D = 1024;
    const long MT = (long)B * T;  // 16384

    const float* X  = (const float*)d_in[0];
    const float* WQ = (const float*)d_in[1];
    const float* WK = (const float*)d_in[2];
    const float* WV = (const float*)d_in[3];
    float* out = (float*)d_out;

    char* ws = (char*)d_ws;
    size_t off = 0;
    auto alloc = [&](size_t bytes) {
        char* p = ws + off;
        off += (bytes + 255) & ~(size_t)255;
        return p;
    };
    short* Xb   = (short*)alloc(MT * H * 2);          // 33.5 MB
    short* Wt   = (short*)alloc(3L * D * H * 2);      //  6.3 MB
    short* Qb   = (short*)alloc(MT * D * 2);          // 33.5 MB
    short* Kb   = (short*)alloc(MT * D * 2);          // 33.5 MB
    short* Vt   = (short*)alloc((long)B * D * T * 2); // 33.5 MB  [b][d][t]
    short* S    = (short*)alloc((long)B * T * T * 2); // 67.1 MB  (only band tiles touched)
    float* Crow = (float*)alloc(MT * 4);              // 64 KB
    float* Vsum = (float*)alloc((long)B * D * 4);     // 32 KB
    if (off > ws_size) return;

    // 1) bf16 conversions
    cvt_f32_bf16<<<(int)(MT * H / 2048), 256, 0, stream>>>(X, Xb);
    transpose_w<<<dim3(32, 32), 256, 0, stream>>>(WQ, Wt);
    transpose_w<<<dim3(32, 32), 256, 0, stream>>>(WK, Wt + (long)D * H);
    transpose_w<<<dim3(32, 32), 256, 0, stream>>>(WV, Wt + 2L * D * H);

    // 2) projections
    dim3 gProj(D / BN, MT / BM, 1);
    gemm_nt<0><<<gProj, 256, 0, stream>>>(Xb, Wt,               Qb, (int)MT, D, H);
    gemm_nt<0><<<gProj, 256, 0, stream>>>(Xb, Wt + (long)D * H, Kb, (int)MT, D, H);
    gemm_nt<1><<<gProj, 256, 0, stream>>>(Xb, Wt + 2L * D * H,  Vt, (int)MT, D, H);

    // 3) V column sums (for the rank-1 masked correction)
    vsum_rows<<<(int)(B * D / 4), 256, 0, stream>>>(Vt, Vsum);

    // 4) band scores (5 column-tiles per 128-row tile)
    gemm_scores<<<dim3(5, 16, B), 256, 0, stream>>>(Qb, Kb, S, 1.f / 32.f);

    // 5) band softmax -> P' = a - c in place, c per row
    softmax_band<<<(int)(MT / 4), 256, 0, stream>>>(S, Crow);

    // 6) band PV + rank-1 correction
    gemm_pv<<<dim3(D / BN, 16, B), 256, 0, stream>>>(S, Vt, Crow, Vsum, out);
}

// Round 3
// 254.304 us; speedup vs baseline: 1.6937x; 1.3298x over previous
//
#include <hip/hip_runtime.h>
#include <hip/hip_bf16.h>
#include <stdint.h>

// ---------- types ----------
typedef __attribute__((ext_vector_type(8))) short bf16x8;
typedef __attribute__((ext_vector_type(4))) short short4v;
typedef __attribute__((ext_vector_type(4))) float f32x4;

#define DEV static __device__ __forceinline__

DEV float bf2f(short u) {
    union { float f; uint32_t i; } c; c.i = ((uint32_t)(uint16_t)u) << 16; return c.f;
}
DEV short f2bf(float f) {
    union { float f; uint32_t i; } c; c.f = f;
    uint32_t i = c.i;
    uint32_t r = i + 0x7FFFu + ((i >> 16) & 1u);   // RNE
    return (short)(r >> 16);
}

DEV void gload_lds16(const short* g, short* l) {
    __builtin_amdgcn_global_load_lds(
        (const __attribute__((address_space(1))) void*)g,
        (__attribute__((address_space(3))) void*)l,
        16, 0, 0);
}

// ---------- fp32 -> bf16 convert (8 elems/thread) ----------
__global__ __launch_bounds__(256)
void cvt_f32_bf16(const float* __restrict__ in, short* __restrict__ out) {
    long i = ((long)blockIdx.x * 256 + threadIdx.x) * 8;
    float4 a = *(const float4*)&in[i];
    float4 b = *(const float4*)&in[i + 4];
    bf16x8 o;
    o[0] = f2bf(a.x); o[1] = f2bf(a.y); o[2] = f2bf(a.z); o[3] = f2bf(a.w);
    o[4] = f2bf(b.x); o[5] = f2bf(b.y); o[6] = f2bf(b.z); o[7] = f2bf(b.w);
    *(bf16x8*)&out[i] = o;
}

// ---------- W [H][D] fp32  ->  Wt [D][H] bf16 ----------
__global__ __launch_bounds__(256)
void transpose_w(const float* __restrict__ W, short* __restrict__ Wt) {
    const int HD = 1024;
    __shared__ float tile[32][33];
    int bx = blockIdx.x, by = blockIdx.y;
    int tx = threadIdx.x & 31, ty = threadIdx.x >> 5;  // 32 x 8
    #pragma unroll
    for (int r = ty; r < 32; r += 8)
        tile[r][tx] = W[(long)(by * 32 + r) * HD + bx * 32 + tx];
    __syncthreads();
    #pragma unroll
    for (int r = ty; r < 32; r += 8)
        Wt[(long)(bx * 32 + r) * HD + by * 32 + tx] = f2bf(tile[tx][r]);
}

// ============================================================================
// 256x256 / BK=64 / 8-wave (2M x 4N) 8-phase GEMM template.
//  - LDS: 2 buf x {A,B} x 2 halves(128x64 bf16) = 128 KiB, linear layout,
//    content XOR-swizzled: LDS[row][c ^ ((row&7)*8 shorts)] = G[row][c]
//    (inverse-swizzle applied on the GLOBAL source address; gload_lds dest
//     stays linear per m104/m108; reads apply the same XOR -> conflict-free)
//  - per K-tile: 4 quadrant-phases (qm,qn) = (0,0),(0,1),(1,1),(1,0),
//    16 MFMA each; counted vmcnt(4) only at the 2 K-tile boundaries.
//  - prefetch issue windows chosen so every LDS overwrite is issued after
//    the region's last reader's closing barrier (WAR-safe).
// EPI: 0 = fused QKV projection, 1 = band scores, 2 = band PV
// ============================================================================

// stage one 128x64 half-tile: 2 x global_load_lds per thread, src pre-swizzled
DEV void stage_half(const short* __restrict__ src, int ld, short* dst, int tid) {
    int rr = tid >> 3;                                    // 0..63
    int cs = ((tid & 7) ^ (rr & 7)) << 3;                 // swizzled src col (shorts)
    short* d = dst + ((tid >> 6) << 9);                   // wave-uniform base (w*512 shorts)
    gload_lds16(src + (long)rr * ld + cs, d);
    gload_lds16(src + (long)(rr + 64) * ld + cs, d + 4096); // second 8KB round
}

DEV bf16x8 ld_frag(const short* half, int rowbase, int ks, int lane) {
    int row = rowbase + (lane & 15);
    int idx = (row << 6) + ks * 32 + ((lane >> 4) << 3);
    idx ^= (lane & 7) << 3;                               // read-side swizzle
    return *(const bf16x8*)&half[idx];
}

#define SB   __builtin_amdgcn_s_barrier()
#define SCHED0 __builtin_amdgcn_sched_barrier(0)
#define LGK0 do { asm volatile("s_waitcnt lgkmcnt(0)" ::: "memory"); SCHED0; } while (0)
#define VM(n) asm volatile("s_waitcnt vmcnt(" #n ")" ::: "memory")
#define PRIO1 __builtin_amdgcn_s_setprio(1)
#define PRIO0 __builtin_amdgcn_s_setprio(0)

#define READ_A(HP, QM)                                                          \
    do { _Pragma("unroll") for (int iq = 0; iq < 4; ++iq)                       \
         _Pragma("unroll") for (int ks = 0; ks < 2; ++ks)                       \
             ra[iq][ks] = ld_frag(HP, (QM)*64 + iq*16, ks, lane); } while (0)

#define READ_B(HP, QN)                                                          \
    do { _Pragma("unroll") for (int jn = 0; jn < 2; ++jn)                       \
         _Pragma("unroll") for (int ks = 0; ks < 2; ++ks)                       \
             rb[QN][jn][ks] = ld_frag(HP, wn1*64 + (QN)*32 + jn*16, ks, lane); } while (0)

#define MFMA_Q(QM, QN)                                                          \
    do { _Pragma("unroll") for (int iq = 0; iq < 4; ++iq)                       \
         _Pragma("unroll") for (int jn = 0; jn < 2; ++jn)                       \
         _Pragma("unroll") for (int ks = 0; ks < 2; ++ks)                       \
             acc[(QM)*4+iq][(QN)*2+jn] = __builtin_amdgcn_mfma_f32_16x16x32_bf16( \
                 ra[iq][ks], rb[QN][jn][ks], acc[(QM)*4+iq][(QN)*2+jn], 0,0,0); } while (0)

template<int EPI>
__global__ __launch_bounds__(512, 2)
void gemm256(const short* __restrict__ Abase, const short* __restrict__ Bbase,
             void* __restrict__ o0, void* __restrict__ o1, void* __restrict__ o2,
             const float* __restrict__ Crow, const float* __restrict__ Vsum)
{
    const int T = 2048, HD = 1024;
    __shared__ __align__(16) short lds[2][2][2][8192];   // [buf][A/B][half] 128 KiB

    const int tid  = threadIdx.x;
    const int lane = tid & 63;
    const int w    = tid >> 6;
    const int wm   = w >> 2;        // 0..1
    const int wn   = w & 3;         // 0..3
    const int wn1  = wn & 1;
    const int bz   = blockIdx.z;

    int m0, n0, klo, khi, ldA, ldB;
    const short *A, *B;
    if (EPI == 0) {
        m0 = blockIdx.y * 256; n0 = blockIdx.x * 256;
        klo = 0; khi = 1024; ldA = HD; ldB = HD;
        A = Abase; B = Bbase;
    } else if (EPI == 1) {
        int mb = blockIdx.y, kb = mb + (int)blockIdx.x - 1;
        if (kb < 0 || kb > 7) return;
        m0 = mb * 256; n0 = kb * 256;
        klo = 0; khi = 1024; ldA = HD; ldB = HD;
        A = Abase + (long)bz * T * HD; B = Bbase + (long)bz * T * HD;
    } else {
        int mb = blockIdx.y;
        m0 = mb * 256; n0 = blockIdx.x * 256;
        klo = max(m0 - 256, 0); khi = min(m0 + 512, T);
        ldA = T; ldB = T;
        A = Abase + (long)bz * T * T; B = Bbase + (long)bz * HD * T;
    }

    const short* Asrc = A + (long)m0 * ldA + klo;
    const short* Bsrc = B + (long)n0 * ldB + klo;
    const short* hA0 = &lds[0][0][wm][0];
    const short* hA1 = &lds[1][0][wm][0];
    const short* hB0 = &lds[0][1][wn >> 1][0];
    const short* hB1 = &lds[1][1][wn >> 1][0];

    auto stA = [&](int bf, int hf, int t) {
        stage_half(Asrc + (long)hf * 128 * ldA + t * 64, ldA, (short*)&lds[bf][0][hf][0], tid); };
    auto stB = [&](int bf, int hf, int t) {
        stage_half(Bsrc + (long)hf * 128 * ldB + t * 64, ldB, (short*)&lds[bf][1][hf][0], tid); };

    f32x4 acc[8][4];
    #pragma unroll
    for (int i = 0; i < 8; ++i)
        #pragma unroll
        for (int j = 0; j < 4; ++j) { acc[i][j][0]=0.f; acc[i][j][1]=0.f; acc[i][j][2]=0.f; acc[i][j][3]=0.f; }
    bf16x8 ra[4][2];
    bf16x8 rb[2][2][2];

    const int NT = (khi - klo) >> 6;    // >= 8, even

    // prologue: tile0 {B0,B1,A0,A1} -> buf0, tile1 {B0,B1} -> buf1  (12 loads)
    stB(0,0,0); stB(0,1,0); stA(0,0,0); stA(0,1,0); stB(1,0,1); stB(1,1,1);
    SCHED0; VM(4); SB;

    for (int i = 0; i < NT/2 - 1; ++i) {
        int t1 = 2*i+1, t2 = 2*i+2, t3 = 2*i+3;
        // p0: tile 2i (buf0) q(0,0)
        READ_A(hA0,0); READ_B(hB0,0); stA(1,0,t1); SCHED0; SB; LGK0; PRIO1; MFMA_Q(0,0); PRIO0; SB; SCHED0;
        // p1: q(0,1)
        READ_B(hB0,1); stA(1,1,t1); SCHED0; SB; LGK0; PRIO1; MFMA_Q(0,1); PRIO0; SB; SCHED0;
        // p2: q(1,1)   (buf0 B-halves dead after p1 -> stage t2 B)
        READ_A(hA0,1); stB(0,0,t2); SCHED0; SB; LGK0; PRIO1; MFMA_Q(1,1); PRIO0; SB; SCHED0;
        // p3: q(1,0)   boundary: tile 2i+1 must be landed for p4
        stB(0,1,t2); SCHED0; SB; LGK0; PRIO1; MFMA_Q(1,0); PRIO0; VM(4); SB; SCHED0;
        // p4: tile 2i+1 (buf1) q(0,0)  (buf0 A-halves dead after p2 -> stage t2 A)
        READ_A(hA1,0); READ_B(hB1,0); stA(0,0,t2); SCHED0; SB; LGK0; PRIO1; MFMA_Q(0,0); PRIO0; SB; SCHED0;
        // p5: q(0,1)
        READ_B(hB1,1); stA(0,1,t2); SCHED0; SB; LGK0; PRIO1; MFMA_Q(0,1); PRIO0; SB; SCHED0;
        // p6: q(1,1)   (buf1 B-halves dead after p5 -> stage t3 B)
        READ_A(hA1,1); stB(1,0,t3); SCHED0; SB; LGK0; PRIO1; MFMA_Q(1,1); PRIO0; SB; SCHED0;
        // p7: q(1,0)   boundary: tile 2i+2 must be landed for next p0
        stB(1,1,t3); SCHED0; SB; LGK0; PRIO1; MFMA_Q(1,0); PRIO0; VM(4); SB; SCHED0;
    }
    {   // peeled final iteration: tiles NT-2 (buf0), NT-1 (buf1); no t2/t3 stages
        int t1 = NT - 1;
        READ_A(hA0,0); READ_B(hB0,0); stA(1,0,t1); SCHED0; SB; LGK0; PRIO1; MFMA_Q(0,0); PRIO0; SB; SCHED0;
        READ_B(hB0,1); stA(1,1,t1); SCHED0; SB; LGK0; PRIO1; MFMA_Q(0,1); PRIO0; SB; SCHED0;
        READ_A(hA0,1); SCHED0; SB; LGK0; PRIO1; MFMA_Q(1,1); PRIO0; SB; SCHED0;
        SB; LGK0; PRIO1; MFMA_Q(1,0); PRIO0; VM(0); SB; SCHED0;
        READ_A(hA1,0); READ_B(hB1,0); SCHED0; SB; LGK0; PRIO1; MFMA_Q(0,0); PRIO0; SB; SCHED0;
        READ_B(hB1,1); SCHED0; SB; LGK0; PRIO1; MFMA_Q(0,1); PRIO0; SB; SCHED0;
        READ_A(hA1,1); SCHED0; SB; LGK0; PRIO1; MFMA_Q(1,1); PRIO0; SB; SCHED0;
        SB; LGK0; PRIO1; MFMA_Q(1,0); PRIO0;
    }

    // ---------------- epilogue ----------------
    const int fr = lane & 15, fq = lane >> 4;
    const int rbase = m0 + wm * 128, cbase = n0 + wn * 64;

    if (EPI == 0) {
        const int wsel = n0 >> 10;          // 0=Q, 1=K, 2=V (block-uniform)
        if (wsel < 2) {
            short* dst = (short*)(wsel ? o1 : o0);
            #pragma unroll
            for (int mi = 0; mi < 8; ++mi)
                #pragma unroll
                for (int ni = 0; ni < 4; ++ni)
                    #pragma unroll
                    for (int r = 0; r < 4; ++r) {
                        int row = rbase + mi * 16 + fq * 4 + r;
                        int col = (cbase + ni * 16 + fr) & 1023;
                        dst[(long)row * HD + col] = f2bf(acc[mi][ni][r]);
                    }
        } else {
            short* Vt = (short*)o2;         // [b][d][t]
            #pragma unroll
            for (int mi = 0; mi < 8; ++mi)
                #pragma unroll
                for (int ni = 0; ni < 4; ++ni) {
                    int col  = (cbase + ni * 16 + fr) & 1023;
                    int row0 = rbase + mi * 16 + fq * 4;
                    int b = row0 >> 11, t = row0 & 2047;
                    short4v v;
                    #pragma unroll
                    for (int r = 0; r < 4; ++r) v[r] = f2bf(acc[mi][ni][r]);
                    *(short4v*)&Vt[((long)b * HD + col) * T + t] = v;
                }
        }
    } else if (EPI == 1) {
        short* S = (short*)o0 + (long)bz * T * T;
        #pragma unroll
        for (int mi = 0; mi < 8; ++mi)
            #pragma unroll
            for (int ni = 0; ni < 4; ++ni)
                #pragma unroll
                for (int r = 0; r < 4; ++r) {
                    int i = rbase + mi * 16 + fq * 4 + r;
                    int j = cbase + ni * 16 + fr;
                    bool keep = (i - j <= 256) && (j - i <= 255);
                    S[(long)i * T + j] = f2bf(keep ? acc[mi][ni][r] * (1.f/32.f) : 0.f);
                }
    } else {
        float* out = (float*)o0;
        #pragma unroll
        for (int mi = 0; mi < 8; ++mi)
            #pragma unroll
            for (int r = 0; r < 4; ++r) {
                int i = rbase + mi * 16 + fq * 4 + r;
                float ci = Crow[bz * T + i];
                #pragma unroll
                for (int ni = 0; ni < 4; ++ni) {
                    int col = cbase + ni * 16 + fr;
                    out[((long)bz * T + i) * HD + col] = acc[mi][ni][r] + ci * Vsum[bz * HD + col];
                }
            }
    }
}

// ---------- band softmax: in place P' = a - c; Crow[i] = c ----------
__global__ __launch_bounds__(256)
void softmax_band(short* __restrict__ S, float* __restrict__ Crow) {
    const int T = 2048;
    int wid = (int)blockIdx.x * 4 + (threadIdx.x >> 6);
    int lane = threadIdx.x & 63;
    int b = wid >> 11, t = wid & 2047;
    int mb = t >> 7;
    int tlo = max(mb - 2, 0) * 128;
    int thi = min(mb + 2, 15) * 128 + 128;
    int nvec = (thi - tlo) >> 3;                   // 48..80
    short* row = S + ((long)b * T + t) * T + tlo;

    bool h0 = lane < nvec;
    bool h1 = lane + 64 < nvec;
    bf16x8 v0, v1;
    float f0[8], f1[8];
    float m = 0.f;                                  // masked zeros always exist
    if (h0) {
        v0 = *(const bf16x8*)&row[lane * 8];
        #pragma unroll
        for (int j = 0; j < 8; ++j) { f0[j] = bf2f(v0[j]); m = fmaxf(m, f0[j]); }
    }
    if (h1) {
        v1 = *(const bf16x8*)&row[(lane + 64) * 8];
        #pragma unroll
        for (int j = 0; j < 8; ++j) { f1[j] = bf2f(v1[j]); m = fmaxf(m, f1[j]); }
    }
    #pragma unroll
    for (int o = 32; o; o >>= 1) m = fmaxf(m, __shfl_xor(m, o));

    float e0[8], e1[8];
    float sum = 0.f;
    if (h0) {
        #pragma unroll
        for (int j = 0; j < 8; ++j) { e0[j] = __expf(f0[j] - m); sum += e0[j]; }
    }
    if (h1) {
        #pragma unroll
        for (int j = 0; j < 8; ++j) { e1[j] = __expf(f1[j] - m); sum += e1[j]; }
    }
    #pragma unroll
    for (int o = 32; o; o >>= 1) sum += __shfl_xor(sum, o);
    float em = __expf(-m);
    sum += (float)(2048 - nvec * 8) * em;
    float inv = 1.f / sum;
    float c = em * inv;

    if (h0) {
        #pragma unroll
        for (int j = 0; j < 8; ++j) v0[j] = f2bf(e0[j] * inv - c);
        *(bf16x8*)&row[lane * 8] = v0;
    }
    if (h1) {
        #pragma unroll
        for (int j = 0; j < 8; ++j) v1[j] = f2bf(e1[j] * inv - c);
        *(bf16x8*)&row[(lane + 64) * 8] = v1;
    }
    if (lane == 0) Crow[wid] = c;
}

// ---------- Vsum[b][d] = sum_t Vt[b][d][t] ----------
__global__ __launch_bounds__(256)
void vsum_rows(const short* __restrict__ Vt, float* __restrict__ Vsum) {
    int rowid = (int)blockIdx.x * 4 + (threadIdx.x >> 6);
    int lane = threadIdx.x & 63;
    const short* r = Vt + (long)rowid * 2048;
    float s = 0.f;
    #pragma unroll
    for (int v = 0; v < 4; ++v) {
        bf16x8 x = *(const bf16x8*)&r[(lane + v * 64) * 8];
        #pragma unroll
        for (int j = 0; j < 8; ++j) s += bf2f(x[j]);
    }
    #pragma unroll
    for (int o = 32; o; o >>= 1) s += __shfl_xor(s, o);
    if (lane == 0) Vsum[rowid] = s;
}

// ---------- launch ----------
extern "C" void kernel_launch(void* const* d_in, const int* in_sizes, int n_in,
                              void* d_out, int out_size, void* d_ws, size_t ws_size,
                              hipStream_t stream) {
    const int B = 8, T = 2048, H = 1024, D = 1024;
    const long MT = (long)B * T;  // 16384

    const float* X  = (const float*)d_in[0];
    const float* WQ = (const float*)d_in[1];
    const float* WK = (const float*)d_in[2];
    const float* WV = (const float*)d_in[3];
    float* out = (float*)d_out;

    char* ws = (char*)d_ws;
    size_t off = 0;
    auto alloc = [&](size_t bytes) {
        char* p = ws + off;
        off += (bytes + 255) & ~(size_t)255;
        return p;
    };
    short* Xb   = (short*)alloc(MT * H * 2);          // 33.5 MB
    short* Wt   = (short*)alloc(3L * D * H * 2);      //  6.3 MB  == B matrix [3072][1024]
    short* Qb   = (short*)alloc(MT * D * 2);          // 33.5 MB
    short* Kb   = (short*)alloc(MT * D * 2);          // 33.5 MB
    short* Vt   = (short*)alloc((long)B * D * T * 2); // 33.5 MB  [b][d][t]
    short* S    = (short*)alloc((long)B * T * T * 2); // 67.1 MB  (band tiles only)
    float* Crow = (float*)alloc(MT * 4);              // 64 KB
    float* Vsum = (float*)alloc((long)B * D * 4);     // 32 KB
    if (off > ws_size) return;

    // 1) bf16 conversions
    cvt_f32_bf16<<<(int)(MT * H / 2048), 256, 0, stream>>>(X, Xb);
    transpose_w<<<dim3(32, 32), 256, 0, stream>>>(WQ, Wt);
    transpose_w<<<dim3(32, 32), 256, 0, stream>>>(WK, Wt + (long)D * H);
    transpose_w<<<dim3(32, 32), 256, 0, stream>>>(WV, Wt + 2L * D * H);

    // 2) fused QKV projection: [16384 x 1024] x [3072 x 1024]^T
    gemm256<0><<<dim3(12, 64, 1), 512, 0, stream>>>(Xb, Wt, Qb, Kb, Vt, nullptr, nullptr);

    // 3) V column sums (rank-1 masked correction)
    vsum_rows<<<(int)(B * D / 4), 256, 0, stream>>>(Vt, Vsum);

    // 4) band scores: 3 x 256-col tiles per 256-row tile
    gemm256<1><<<dim3(3, 8, B), 512, 0, stream>>>(Qb, Kb, S, nullptr, nullptr, nullptr, nullptr);

    // 5) band softmax -> P' = a - c in place, c per row
    softmax_band<<<(int)(MT / 4), 256, 0, stream>>>(S, Crow);

    // 6) band PV + rank-1 correction
    gemm256<2><<<dim3(4, 8, B), 512, 0, stream>>>(S, Vt, out, nullptr, nullptr, Crow, Vsum);
}

// Round 4
// 236.860 us; speedup vs baseline: 1.8184x; 1.0736x over previous
//
#include <hip/hip_runtime.h>
#include <hip/hip_bf16.h>
#include <stdint.h>

// ---------- types ----------
typedef __attribute__((ext_vector_type(8))) short bf16x8;
typedef __attribute__((ext_vector_type(4))) short short4v;
typedef __attribute__((ext_vector_type(4))) float f32x4;

#define DEV static __device__ __forceinline__

DEV float bf2f(short u) {
    union { float f; uint32_t i; } c; c.i = ((uint32_t)(uint16_t)u) << 16; return c.f;
}
DEV short f2bf(float f) {
    union { float f; uint32_t i; } c; c.f = f;
    uint32_t i = c.i;
    uint32_t r = i + 0x7FFFu + ((i >> 16) & 1u);   // RNE
    return (short)(r >> 16);
}

DEV void gload_lds16(const short* g, short* l) {
    __builtin_amdgcn_global_load_lds(
        (const __attribute__((address_space(1))) void*)g,
        (__attribute__((address_space(3))) void*)l,
        16, 0, 0);
}

// ---------- fp32 -> bf16 convert (8 elems/thread) ----------
__global__ __launch_bounds__(256)
void cvt_f32_bf16(const float* __restrict__ in, short* __restrict__ out) {
    long i = ((long)blockIdx.x * 256 + threadIdx.x) * 8;
    float4 a = *(const float4*)&in[i];
    float4 b = *(const float4*)&in[i + 4];
    bf16x8 o;
    o[0] = f2bf(a.x); o[1] = f2bf(a.y); o[2] = f2bf(a.z); o[3] = f2bf(a.w);
    o[4] = f2bf(b.x); o[5] = f2bf(b.y); o[6] = f2bf(b.z); o[7] = f2bf(b.w);
    *(bf16x8*)&out[i] = o;
}

// ---------- W [H][D] fp32  ->  Wt [D][H] bf16 ----------
__global__ __launch_bounds__(256)
void transpose_w(const float* __restrict__ W, short* __restrict__ Wt) {
    const int HD = 1024;
    __shared__ float tile[32][33];
    int bx = blockIdx.x, by = blockIdx.y;
    int tx = threadIdx.x & 31, ty = threadIdx.x >> 5;  // 32 x 8
    #pragma unroll
    for (int r = ty; r < 32; r += 8)
        tile[r][tx] = W[(long)(by * 32 + r) * HD + bx * 32 + tx];
    __syncthreads();
    #pragma unroll
    for (int r = ty; r < 32; r += 8)
        Wt[(long)(bx * 32 + r) * HD + by * 32 + tx] = f2bf(tile[tx][r]);
}

// ============================================================================
// 256x256 / BK=64 / 8-wave 8-phase GEMM, pipelined reads + counted lgkmcnt.
// Per phase: ONE barrier; B-fragment reads issued one phase early into the
// disjoint rb[QN] bank; lgkmcnt(4) leaves them in flight under MFMA.
// vmcnt(2) placed BEFORE the barrier that precedes any early read of a
// freshly staged buffer (all waves retire staging before anyone samples LDS).
// Quadrant order (0,0),(0,1),(1,0),(1,1) so ra (A-quadrant) is single-buffered.
// ============================================================================

DEV void stage_half(const short* __restrict__ src, int ld, short* dst, int tid) {
    int rr = tid >> 3;                                    // 0..63
    int cs = ((tid & 7) ^ (rr & 7)) << 3;                 // swizzled src col (shorts)
    short* d = dst + ((tid >> 6) << 9);                   // wave-uniform base
    gload_lds16(src + (long)rr * ld + cs, d);
    gload_lds16(src + (long)(rr + 64) * ld + cs, d + 4096);
}

DEV bf16x8 ld_frag(const short* half, int rowbase, int ks, int lane) {
    int row = rowbase + (lane & 15);
    int idx = (row << 6) + ks * 32 + ((lane >> 4) << 3);
    idx ^= (lane & 7) << 3;                               // read-side swizzle
    return *(const bf16x8*)&half[idx];
}

#define SCHED0 __builtin_amdgcn_sched_barrier(0)
#define SBAR do { SCHED0; __builtin_amdgcn_s_barrier(); SCHED0; } while (0)
#define LGK(n) do { asm volatile("s_waitcnt lgkmcnt(" #n ")" ::: "memory"); SCHED0; } while (0)
#define VM(n)  do { asm volatile("s_waitcnt vmcnt(" #n ")" ::: "memory"); SCHED0; } while (0)
#define PRIO1 __builtin_amdgcn_s_setprio(1)
#define PRIO0 __builtin_amdgcn_s_setprio(0)

#define READ_A(HP, QM)                                                          \
    do { _Pragma("unroll") for (int iq = 0; iq < 4; ++iq)                       \
         _Pragma("unroll") for (int ks = 0; ks < 2; ++ks)                       \
             ra[iq][ks] = ld_frag(HP, (QM)*64 + iq*16, ks, lane); } while (0)

#define READ_B(HP, QN)                                                          \
    do { _Pragma("unroll") for (int jn = 0; jn < 2; ++jn)                       \
         _Pragma("unroll") for (int ks = 0; ks < 2; ++ks)                       \
             rb[QN][jn][ks] = ld_frag(HP, wn1*64 + (QN)*32 + jn*16, ks, lane); } while (0)

#define MFMA_Q(QM, QN)                                                          \
    do { _Pragma("unroll") for (int iq = 0; iq < 4; ++iq)                       \
         _Pragma("unroll") for (int jn = 0; jn < 2; ++jn)                       \
         _Pragma("unroll") for (int ks = 0; ks < 2; ++ks)                       \
             acc[(QM)*4+iq][(QN)*2+jn] = __builtin_amdgcn_mfma_f32_16x16x32_bf16( \
                 ra[iq][ks], rb[QN][jn][ks], acc[(QM)*4+iq][(QN)*2+jn], 0,0,0); } while (0)

template<int EPI>
__global__ __launch_bounds__(512, 2)
void gemm256(const short* __restrict__ Abase, const short* __restrict__ Bbase,
             void* __restrict__ o0, void* __restrict__ o1, void* __restrict__ o2,
             const float* __restrict__ Crow, const float* __restrict__ Vsum)
{
    const int T = 2048, HD = 1024;
    __shared__ __align__(16) short lds[2][2][2][8192];   // [buf][A/B][half] 128 KiB

    const int tid  = threadIdx.x;
    const int lane = tid & 63;
    const int w    = tid >> 6;
    const int wm   = w >> 2;        // 0..1
    const int wn   = w & 3;         // 0..3
    const int wn1  = wn & 1;

    int m0, n0, klo, khi, ldA, ldB, bz;
    const short *A, *B;
    if (EPI == 0) {
        int p = (int)blockIdx.x + 12 * (int)blockIdx.y;   // 0..767
        int lid = (p & 7) * 96 + (p >> 3);                // XCD-chunked (768%8==0)
        m0 = (lid / 12) * 256; n0 = (lid % 12) * 256;
        klo = 0; khi = 1024; ldA = HD; ldB = HD; bz = 0;
        A = Abase; B = Bbase;
    } else if (EPI == 1) {
        int p = (int)blockIdx.x + 3 * ((int)blockIdx.y + 8 * (int)blockIdx.z); // 0..191
        bz = p & 7; int rem = p >> 3;                     // batch -> XCD chunk
        int mb = rem / 3, kb = mb + rem % 3 - 1;
        if (kb < 0 || kb > 7) return;
        m0 = mb * 256; n0 = kb * 256;
        klo = 0; khi = 1024; ldA = HD; ldB = HD;
        A = Abase + (long)bz * T * HD; B = Bbase + (long)bz * T * HD;
    } else {
        int p = (int)blockIdx.x + 4 * ((int)blockIdx.y + 8 * (int)blockIdx.z); // 0..255
        bz = p & 7; int rem = p >> 3;
        int mb = rem / 4;
        m0 = mb * 256; n0 = (rem % 4) * 256;
        klo = max(m0 - 256, 0); khi = min(m0 + 512, T);
        ldA = T; ldB = T;
        A = Abase + (long)bz * T * T; B = Bbase + (long)bz * HD * T;
    }

    const short* Asrc = A + (long)m0 * ldA + klo;
    const short* Bsrc = B + (long)n0 * ldB + klo;
    const short* hA0 = &lds[0][0][wm][0];
    const short* hA1 = &lds[1][0][wm][0];
    const short* hB0 = &lds[0][1][wn >> 1][0];
    const short* hB1 = &lds[1][1][wn >> 1][0];

    auto stA = [&](int bf, int hf, int t) {
        stage_half(Asrc + (long)hf * 128 * ldA + t * 64, ldA, (short*)&lds[bf][0][hf][0], tid); };
    auto stB = [&](int bf, int hf, int t) {
        stage_half(Bsrc + (long)hf * 128 * ldB + t * 64, ldB, (short*)&lds[bf][1][hf][0], tid); };

    f32x4 acc[8][4];
    #pragma unroll
    for (int i = 0; i < 8; ++i)
        #pragma unroll
        for (int j = 0; j < 4; ++j) { acc[i][j][0]=0.f; acc[i][j][1]=0.f; acc[i][j][2]=0.f; acc[i][j][3]=0.f; }
    bf16x8 ra[4][2];
    bf16x8 rb[2][2][2];

    const int NT = (khi - klo) >> 6;    // >= 2, even

    // prologue: tile0 {A,B} -> buf0, tile1 {B} -> buf1
    stB(0,0,0); stB(0,1,0); stA(0,0,0); stA(0,1,0); stB(1,0,1); stB(1,1,1);
    SCHED0; VM(4); SBAR;                 // buf0 landed for ALL waves
    READ_B(hB0, 0); SCHED0;              // early B-q0 for p0

    #pragma unroll 1
    for (int i = 0; i < NT/2 - 1; ++i) {
        int t1 = 2*i+1, t2 = 2*i+2, t3 = 2*i+3;
        // p0: tile 2i (buf0)
        SBAR; READ_A(hA0,0); SCHED0; READ_B(hB0,1); SCHED0; stA(1,0,t1);
        LGK(4); PRIO1; MFMA_Q(0,0); PRIO0; SCHED0;
        // p1
        SBAR; stA(1,1,t1); LGK(0); PRIO1; MFMA_Q(0,1); PRIO0; SCHED0;
        // p2  (buf0-B dead after p1 -> stage t2 B)
        SBAR; READ_A(hA0,1); SCHED0; stB(0,0,t2); LGK(0);
        PRIO1; MFMA_Q(1,0); PRIO0; SCHED0; VM(2); SCHED0;   // retire all but own stage
        // p3  (early B-q0 of buf1: safe, all waves did VM(2) before this barrier)
        SBAR; READ_B(hB1,0); SCHED0; stB(0,1,t2);
        PRIO1; MFMA_Q(1,1); PRIO0; SCHED0;
        // p4: tile 2i+1 (buf1)  (buf0-A dead after p2 -> stage t2 A)
        SBAR; READ_A(hA1,0); SCHED0; READ_B(hB1,1); SCHED0; stA(0,0,t2);
        LGK(4); PRIO1; MFMA_Q(0,0); PRIO0; SCHED0;
        // p5
        SBAR; stA(0,1,t2); LGK(0); PRIO1; MFMA_Q(0,1); PRIO0; SCHED0;
        // p6
        SBAR; READ_A(hA1,1); SCHED0; stB(1,0,t3); LGK(0);
        PRIO1; MFMA_Q(1,0); PRIO0; SCHED0; VM(2); SCHED0;
        // p7  (early B-q0 of buf0 for next iter)
        SBAR; READ_B(hB0,0); SCHED0; stB(1,1,t3);
        PRIO1; MFMA_Q(1,1); PRIO0; SCHED0;
    }
    {   // peeled final: tiles NT-2 (buf0), NT-1 (buf1); A of NT-1 staged here
        int t1 = NT - 1;
        SBAR; READ_A(hA0,0); SCHED0; READ_B(hB0,1); SCHED0; stA(1,0,t1);
        LGK(4); PRIO1; MFMA_Q(0,0); PRIO0; SCHED0;
        SBAR; stA(1,1,t1); LGK(0); PRIO1; MFMA_Q(0,1); PRIO0; SCHED0;
        SBAR; READ_A(hA0,1); SCHED0; LGK(0);
        PRIO1; MFMA_Q(1,0); PRIO0; SCHED0; VM(0); SCHED0;   // drain: buf1 fully landed
        SBAR; READ_B(hB1,0); SCHED0; PRIO1; MFMA_Q(1,1); PRIO0; SCHED0;
        SBAR; READ_A(hA1,0); SCHED0; READ_B(hB1,1); SCHED0;
        LGK(4); PRIO1; MFMA_Q(0,0); PRIO0; SCHED0;
        SBAR; LGK(0); PRIO1; MFMA_Q(0,1); PRIO0; SCHED0;
        SBAR; READ_A(hA1,1); SCHED0; LGK(0); PRIO1; MFMA_Q(1,0); PRIO0; SCHED0;
        SBAR; PRIO1; MFMA_Q(1,1); PRIO0; SCHED0;
    }

    // ---------------- epilogue ----------------
    const int fr = lane & 15, fq = lane >> 4;
    const int rbase = m0 + wm * 128, cbase = n0 + wn * 64;

    if (EPI == 0) {
        const int wsel = n0 >> 10;          // 0=Q, 1=K, 2=V (block-uniform)
        if (wsel < 2) {
            short* dst = (short*)(wsel ? o1 : o0);
            #pragma unroll
            for (int mi = 0; mi < 8; ++mi)
                #pragma unroll
                for (int ni = 0; ni < 4; ++ni)
                    #pragma unroll
                    for (int r = 0; r < 4; ++r) {
                        int row = rbase + mi * 16 + fq * 4 + r;
                        int col = (cbase + ni * 16 + fr) & 1023;
                        dst[(long)row * HD + col] = f2bf(acc[mi][ni][r]);
                    }
        } else {
            short* Vt = (short*)o2;         // [b][d][t]
            #pragma unroll
            for (int mi = 0; mi < 8; ++mi)
                #pragma unroll
                for (int ni = 0; ni < 4; ++ni) {
                    int col  = (cbase + ni * 16 + fr) & 1023;
                    int row0 = rbase + mi * 16 + fq * 4;
                    int b = row0 >> 11, t = row0 & 2047;
                    short4v v;
                    #pragma unroll
                    for (int r = 0; r < 4; ++r) v[r] = f2bf(acc[mi][ni][r]);
                    *(short4v*)&Vt[((long)b * HD + col) * T + t] = v;
                }
        }
    } else if (EPI == 1) {
        short* S = (short*)o0 + (long)bz * T * T;
        #pragma unroll
        for (int mi = 0; mi < 8; ++mi)
            #pragma unroll
            for (int ni = 0; ni < 4; ++ni)
                #pragma unroll
                for (int r = 0; r < 4; ++r) {
                    int i = rbase + mi * 16 + fq * 4 + r;
                    int j = cbase + ni * 16 + fr;
                    bool keep = (i - j <= 256) && (j - i <= 255);
                    S[(long)i * T + j] = f2bf(keep ? acc[mi][ni][r] * (1.f/32.f) : 0.f);
                }
    } else {
        float* out = (float*)o0;
        #pragma unroll
        for (int mi = 0; mi < 8; ++mi)
            #pragma unroll
            for (int r = 0; r < 4; ++r) {
                int i = rbase + mi * 16 + fq * 4 + r;
                float ci = Crow[bz * T + i];
                #pragma unroll
                for (int ni = 0; ni < 4; ++ni) {
                    int col = cbase + ni * 16 + fr;
                    out[((long)bz * T + i) * HD + col] = acc[mi][ni][r] + ci * Vsum[bz * HD + col];
                }
            }
    }
}

// ---------- band softmax: in place P' = a - c; Crow[i] = c ----------
__global__ __launch_bounds__(256)
void softmax_band(short* __restrict__ S, float* __restrict__ Crow) {
    const int T = 2048;
    int wid = (int)blockIdx.x * 4 + (threadIdx.x >> 6);
    int lane = threadIdx.x & 63;
    int b = wid >> 11, t = wid & 2047;
    int mb = t >> 7;
    int tlo = max(mb - 2, 0) * 128;
    int thi = min(mb + 2, 15) * 128 + 128;
    int nvec = (thi - tlo) >> 3;                   // 48..80
    short* row = S + ((long)b * T + t) * T + tlo;

    bool h0 = lane < nvec;
    bool h1 = lane + 64 < nvec;
    bf16x8 v0, v1;
    float f0[8], f1[8];
    float m = 0.f;                                  // masked zeros always exist
    if (h0) {
        v0 = *(const bf16x8*)&row[lane * 8];
        #pragma unroll
        for (int j = 0; j < 8; ++j) { f0[j] = bf2f(v0[j]); m = fmaxf(m, f0[j]); }
    }
    if (h1) {
        v1 = *(const bf16x8*)&row[(lane + 64) * 8];
        #pragma unroll
        for (int j = 0; j < 8; ++j) { f1[j] = bf2f(v1[j]); m = fmaxf(m, f1[j]); }
    }
    #pragma unroll
    for (int o = 32; o; o >>= 1) m = fmaxf(m, __shfl_xor(m, o));

    float e0[8], e1[8];
    float sum = 0.f;
    if (h0) {
        #pragma unroll
        for (int j = 0; j < 8; ++j) { e0[j] = __expf(f0[j] - m); sum += e0[j]; }
    }
    if (h1) {
        #pragma unroll
        for (int j = 0; j < 8; ++j) { e1[j] = __expf(f1[j] - m); sum += e1[j]; }
    }
    #pragma unroll
    for (int o = 32; o; o >>= 1) sum += __shfl_xor(sum, o);
    float em = __expf(-m);
    sum += (float)(2048 - nvec * 8) * em;
    float inv = 1.f / sum;
    float c = em * inv;

    if (h0) {
        #pragma unroll
        for (int j = 0; j < 8; ++j) v0[j] = f2bf(e0[j] * inv - c);
        *(bf16x8*)&row[lane * 8] = v0;
    }
    if (h1) {
        #pragma unroll
        for (int j = 0; j < 8; ++j) v1[j] = f2bf(e1[j] * inv - c);
        *(bf16x8*)&row[(lane + 64) * 8] = v1;
    }
    if (lane == 0) Crow[wid] = c;
}

// ---------- Vsum[b][d] = sum_t Vt[b][d][t] ----------
__global__ __launch_bounds__(256)
void vsum_rows(const short* __restrict__ Vt, float* __restrict__ Vsum) {
    int rowid = (int)blockIdx.x * 4 + (threadIdx.x >> 6);
    int lane = threadIdx.x & 63;
    const short* r = Vt + (long)rowid * 2048;
    float s = 0.f;
    #pragma unroll
    for (int v = 0; v < 4; ++v) {
        bf16x8 x = *(const bf16x8*)&r[(lane + v * 64) * 8];
        #pragma unroll
        for (int j = 0; j < 8; ++j) s += bf2f(x[j]);
    }
    #pragma unroll
    for (int o = 32; o; o >>= 1) s += __shfl_xor(s, o);
    if (lane == 0) Vsum[rowid] = s;
}

// ---------- launch ----------
extern "C" void kernel_launch(void* const* d_in, const int* in_sizes, int n_in,
                              void* d_out, int out_size, void* d_ws, size_t ws_size,
                              hipStream_t stream) {
    const int B = 8, T = 2048, H = 1024, D = 1024;
    const long MT = (long)B * T;  // 16384

    const float* X  = (const float*)d_in[0];
    const float* WQ = (const float*)d_in[1];
    const float* WK = (const float*)d_in[2];
    const float* WV = (const float*)d_in[3];
    float* out = (float*)d_out;

    char* ws = (char*)d_ws;
    size_t off = 0;
    auto alloc = [&](size_t bytes) {
        char* p = ws + off;
        off += (bytes + 255) & ~(size_t)255;
        return p;
    };
    short* Xb   = (short*)alloc(MT * H * 2);          // 33.5 MB
    short* Wt   = (short*)alloc(3L * D * H * 2);      //  6.3 MB  == B matrix [3072][1024]
    short* Qb   = (short*)alloc(MT * D * 2);          // 33.5 MB
    short* Kb   = (short*)alloc(MT * D * 2);          // 33.5 MB
    short* Vt   = (short*)alloc((long)B * D * T * 2); // 33.5 MB  [b][d][t]
    short* S    = (short*)alloc((long)B * T * T * 2); // 67.1 MB  (band tiles only)
    float* Crow = (float*)alloc(MT * 4);              // 64 KB
    float* Vsum = (float*)alloc((long)B * D * 4);     // 32 KB
    if (off > ws_size) return;

    // 1) bf16 conversions
    cvt_f32_bf16<<<(int)(MT * H / 2048), 256, 0, stream>>>(X, Xb);
    transpose_w<<<dim3(32, 32), 256, 0, stream>>>(WQ, Wt);
    transpose_w<<<dim3(32, 32), 256, 0, stream>>>(WK, Wt + (long)D * H);
    transpose_w<<<dim3(32, 32), 256, 0, stream>>>(WV, Wt + 2L * D * H);

    // 2) fused QKV projection: [16384 x 1024] x [3072 x 1024]^T
    gemm256<0><<<dim3(12, 64, 1), 512, 0, stream>>>(Xb, Wt, Qb, Kb, Vt, nullptr, nullptr);

    // 3) V column sums (rank-1 masked correction)
    vsum_rows<<<(int)(B * D / 4), 256, 0, stream>>>(Vt, Vsum);

    // 4) band scores: 3 x 256-col tiles per 256-row tile
    gemm256<1><<<dim3(3, 8, B), 512, 0, stream>>>(Qb, Kb, S, nullptr, nullptr, nullptr, nullptr);

    // 5) band softmax -> P' = a - c in place, c per row
    softmax_band<<<(int)(MT / 4), 256, 0, stream>>>(S, Crow);

    // 6) band PV + rank-1 correction
    gemm256<2><<<dim3(4, 8, B), 512, 0, stream>>>(S, Vt, out, nullptr, nullptr, Crow, Vsum);
}

// Round 5
// 212.546 us; speedup vs baseline: 2.0264x; 1.1144x over previous
//
#include <hip/hip_runtime.h>
#include <hip/hip_bf16.h>
#include <stdint.h>

// ---------- types ----------
typedef __attribute__((ext_vector_type(8))) short bf16x8;
typedef __attribute__((ext_vector_type(4))) short short4v;
typedef __attribute__((ext_vector_type(4))) float f32x4;

#define DEV static __device__ __forceinline__

DEV float bf2f(short u) {
    union { float f; uint32_t i; } c; c.i = ((uint32_t)(uint16_t)u) << 16; return c.f;
}
DEV short f2bf(float f) {
    union { float f; uint32_t i; } c; c.f = f;
    uint32_t i = c.i;
    uint32_t r = i + 0x7FFFu + ((i >> 16) & 1u);   // RNE
    return (short)(r >> 16);
}

DEV void gload_lds16(const short* g, short* l) {
    __builtin_amdgcn_global_load_lds(
        (const __attribute__((address_space(1))) void*)g,
        (__attribute__((address_space(3))) void*)l,
        16, 0, 0);
}

// ---------- fp32 -> bf16 convert (8 elems/thread) ----------
__global__ __launch_bounds__(256)
void cvt_f32_bf16(const float* __restrict__ in, short* __restrict__ out) {
    long i = ((long)blockIdx.x * 256 + threadIdx.x) * 8;
    float4 a = *(const float4*)&in[i];
    float4 b = *(const float4*)&in[i + 4];
    bf16x8 o;
    o[0] = f2bf(a.x); o[1] = f2bf(a.y); o[2] = f2bf(a.z); o[3] = f2bf(a.w);
    o[4] = f2bf(b.x); o[5] = f2bf(b.y); o[6] = f2bf(b.z); o[7] = f2bf(b.w);
    *(bf16x8*)&out[i] = o;
}

// ---------- W [H][D] fp32  ->  Wt [D][H] bf16 ----------
__global__ __launch_bounds__(256)
void transpose_w(const float* __restrict__ W, short* __restrict__ Wt) {
    const int HD = 1024;
    __shared__ float tile[32][33];
    int bx = blockIdx.x, by = blockIdx.y;
    int tx = threadIdx.x & 31, ty = threadIdx.x >> 5;  // 32 x 8
    #pragma unroll
    for (int r = ty; r < 32; r += 8)
        tile[r][tx] = W[(long)(by * 32 + r) * HD + bx * 32 + tx];
    __syncthreads();
    #pragma unroll
    for (int r = ty; r < 32; r += 8)
        Wt[(long)(bx * 32 + r) * HD + by * 32 + tx] = f2bf(tile[tx][r]);
}

// ---------- reduce 4 fp32 K-slices of Mt and cast to bf16 ----------
__global__ __launch_bounds__(256)
void reduce_mt(const float* __restrict__ Mpart, short* __restrict__ MTb) {
    const long SL = 1024L * 1024;
    long i = ((long)blockIdx.x * 256 + threadIdx.x) * 8;
    float s[8];
    #pragma unroll
    for (int j = 0; j < 8; ++j) s[j] = 0.f;
    #pragma unroll
    for (int sl = 0; sl < 4; ++sl) {
        float4 a = *(const float4*)&Mpart[sl * SL + i];
        float4 b = *(const float4*)&Mpart[sl * SL + i + 4];
        s[0] += a.x; s[1] += a.y; s[2] += a.z; s[3] += a.w;
        s[4] += b.x; s[5] += b.y; s[6] += b.z; s[7] += b.w;
    }
    bf16x8 o;
    #pragma unroll
    for (int j = 0; j < 8; ++j) o[j] = f2bf(s[j]);
    *(bf16x8*)&MTb[i] = o;
}

// ============================================================================
// 256x256 / BK=64 / 8-wave 8-phase GEMM, pipelined reads + counted lgkmcnt.
// EPI: 0 = fused [G|V] projection, 1 = band scores (B = Xb), 2 = band PV,
//      3 = Mt split-K partial (fp32 out per K-slice)
// ============================================================================

DEV void stage_half(const short* __restrict__ src, int ld, short* dst, int tid) {
    int rr = tid >> 3;                                    // 0..63
    int cs = ((tid & 7) ^ (rr & 7)) << 3;                 // swizzled src col (shorts)
    short* d = dst + ((tid >> 6) << 9);                   // wave-uniform base
    gload_lds16(src + (long)rr * ld + cs, d);
    gload_lds16(src + (long)(rr + 64) * ld + cs, d + 4096);
}

DEV bf16x8 ld_frag(const short* half, int rowbase, int ks, int lane) {
    int row = rowbase + (lane & 15);
    int idx = (row << 6) + ks * 32 + ((lane >> 4) << 3);
    idx ^= (lane & 7) << 3;                               // read-side swizzle
    return *(const bf16x8*)&half[idx];
}

#define SCHED0 __builtin_amdgcn_sched_barrier(0)
#define SBAR do { SCHED0; __builtin_amdgcn_s_barrier(); SCHED0; } while (0)
#define LGK(n) do { asm volatile("s_waitcnt lgkmcnt(" #n ")" ::: "memory"); SCHED0; } while (0)
#define VM(n)  do { asm volatile("s_waitcnt vmcnt(" #n ")" ::: "memory"); SCHED0; } while (0)
#define PRIO1 __builtin_amdgcn_s_setprio(1)
#define PRIO0 __builtin_amdgcn_s_setprio(0)

#define READ_A(HP, QM)                                                          \
    do { _Pragma("unroll") for (int iq = 0; iq < 4; ++iq)                       \
         _Pragma("unroll") for (int ks = 0; ks < 2; ++ks)                       \
             ra[iq][ks] = ld_frag(HP, (QM)*64 + iq*16, ks, lane); } while (0)

#define READ_B(HP, QN)                                                          \
    do { _Pragma("unroll") for (int jn = 0; jn < 2; ++jn)                       \
         _Pragma("unroll") for (int ks = 0; ks < 2; ++ks)                       \
             rb[QN][jn][ks] = ld_frag(HP, wn1*64 + (QN)*32 + jn*16, ks, lane); } while (0)

#define MFMA_Q(QM, QN)                                                          \
    do { _Pragma("unroll") for (int iq = 0; iq < 4; ++iq)                       \
         _Pragma("unroll") for (int jn = 0; jn < 2; ++jn)                       \
         _Pragma("unroll") for (int ks = 0; ks < 2; ++ks)                       \
             acc[(QM)*4+iq][(QN)*2+jn] = __builtin_amdgcn_mfma_f32_16x16x32_bf16( \
                 ra[iq][ks], rb[QN][jn][ks], acc[(QM)*4+iq][(QN)*2+jn], 0,0,0); } while (0)

template<int EPI>
__global__ __launch_bounds__(512, 2)
void gemm256(const short* __restrict__ Abase, const short* __restrict__ Bbase,
             void* __restrict__ o0, void* __restrict__ o1, void* __restrict__ o2,
             const float* __restrict__ Crow, const float* __restrict__ Vsum)
{
    const int T = 2048, HD = 1024;
    __shared__ __align__(16) short lds[2][2][2][8192];   // [buf][A/B][half] 128 KiB

    const int tid  = threadIdx.x;
    const int lane = tid & 63;
    const int w    = tid >> 6;
    const int wm   = w >> 2;        // 0..1
    const int wn   = w & 3;         // 0..3
    const int wn1  = wn & 1;

    int m0, n0, klo, khi, ldA, ldB, bz;
    const short *A, *B;
    if (EPI == 0) {
        int p = (int)blockIdx.x + 8 * (int)blockIdx.y;    // 0..511
        int lid = (p & 7) * 64 + (p >> 3);                // XCD-chunked (512%8==0)
        m0 = (lid >> 3) * 256; n0 = (lid & 7) * 256;
        klo = 0; khi = 1024; ldA = HD; ldB = HD; bz = 0;
        A = Abase; B = Bbase;
    } else if (EPI == 1) {
        int p = (int)blockIdx.x + 3 * ((int)blockIdx.y + 8 * (int)blockIdx.z); // 0..191
        bz = p & 7; int rem = p >> 3;                     // batch -> XCD chunk
        int mb = rem / 3, kb = mb + rem % 3 - 1;
        if (kb < 0 || kb > 7) return;
        m0 = mb * 256; n0 = kb * 256;
        klo = 0; khi = 1024; ldA = HD; ldB = HD;
        A = Abase + (long)bz * T * HD; B = Bbase + (long)bz * T * HD;
    } else if (EPI == 2) {
        int p = (int)blockIdx.x + 4 * ((int)blockIdx.y + 8 * (int)blockIdx.z); // 0..255
        bz = p & 7; int rem = p >> 3;
        int mb = rem / 4;
        m0 = mb * 256; n0 = (rem % 4) * 256;
        klo = max(m0 - 256, 0); khi = min(m0 + 512, T);
        ldA = T; ldB = T;
        A = Abase + (long)bz * T * T; B = Bbase + (long)bz * HD * T;
    } else {
        // Mt split-K partial: z = K-slice
        m0 = blockIdx.y * 256; n0 = blockIdx.x * 256;
        klo = (int)blockIdx.z * 256; khi = klo + 256;
        ldA = HD; ldB = HD; bz = 0;
        A = Abase; B = Bbase;
    }

    const short* Asrc = A + (long)m0 * ldA + klo;
    const short* Bsrc = B + (long)n0 * ldB + klo;
    const short* hA0 = &lds[0][0][wm][0];
    const short* hA1 = &lds[1][0][wm][0];
    const short* hB0 = &lds[0][1][wn >> 1][0];
    const short* hB1 = &lds[1][1][wn >> 1][0];

    auto stA = [&](int bf, int hf, int t) {
        stage_half(Asrc + (long)hf * 128 * ldA + t * 64, ldA, (short*)&lds[bf][0][hf][0], tid); };
    auto stB = [&](int bf, int hf, int t) {
        stage_half(Bsrc + (long)hf * 128 * ldB + t * 64, ldB, (short*)&lds[bf][1][hf][0], tid); };

    f32x4 acc[8][4];
    #pragma unroll
    for (int i = 0; i < 8; ++i)
        #pragma unroll
        for (int j = 0; j < 4; ++j) { acc[i][j][0]=0.f; acc[i][j][1]=0.f; acc[i][j][2]=0.f; acc[i][j][3]=0.f; }
    bf16x8 ra[4][2];
    bf16x8 rb[2][2][2];

    const int NT = (khi - klo) >> 6;    // >= 2, even

    // prologue: tile0 {A,B} -> buf0, tile1 {B} -> buf1
    stB(0,0,0); stB(0,1,0); stA(0,0,0); stA(0,1,0); stB(1,0,1); stB(1,1,1);
    SCHED0; VM(4); SBAR;                 // buf0 landed for ALL waves
    READ_B(hB0, 0); SCHED0;              // early B-q0 for p0

    #pragma unroll 1
    for (int i = 0; i < NT/2 - 1; ++i) {
        int t1 = 2*i+1, t2 = 2*i+2, t3 = 2*i+3;
        // p0: tile 2i (buf0)
        SBAR; READ_A(hA0,0); SCHED0; READ_B(hB0,1); SCHED0; stA(1,0,t1);
        LGK(4); PRIO1; MFMA_Q(0,0); PRIO0; SCHED0;
        // p1
        SBAR; stA(1,1,t1); LGK(0); PRIO1; MFMA_Q(0,1); PRIO0; SCHED0;
        // p2  (buf0-B dead after p1 -> stage t2 B)
        SBAR; READ_A(hA0,1); SCHED0; stB(0,0,t2); LGK(0);
        PRIO1; MFMA_Q(1,0); PRIO0; SCHED0; VM(2); SCHED0;   // retire all but own stage
        // p3  (early B-q0 of buf1: safe, all waves did VM(2) before this barrier)
        SBAR; READ_B(hB1,0); SCHED0; stB(0,1,t2);
        PRIO1; MFMA_Q(1,1); PRIO0; SCHED0;
        // p4: tile 2i+1 (buf1)  (buf0-A dead after p2 -> stage t2 A)
        SBAR; READ_A(hA1,0); SCHED0; READ_B(hB1,1); SCHED0; stA(0,0,t2);
        LGK(4); PRIO1; MFMA_Q(0,0); PRIO0; SCHED0;
        // p5
        SBAR; stA(0,1,t2); LGK(0); PRIO1; MFMA_Q(0,1); PRIO0; SCHED0;
        // p6
        SBAR; READ_A(hA1,1); SCHED0; stB(1,0,t3); LGK(0);
        PRIO1; MFMA_Q(1,0); PRIO0; SCHED0; VM(2); SCHED0;
        // p7  (early B-q0 of buf0 for next iter)
        SBAR; READ_B(hB0,0); SCHED0; stB(1,1,t3);
        PRIO1; MFMA_Q(1,1); PRIO0; SCHED0;
    }
    {   // peeled final: tiles NT-2 (buf0), NT-1 (buf1); A of NT-1 staged here
        int t1 = NT - 1;
        SBAR; READ_A(hA0,0); SCHED0; READ_B(hB0,1); SCHED0; stA(1,0,t1);
        LGK(4); PRIO1; MFMA_Q(0,0); PRIO0; SCHED0;
        SBAR; stA(1,1,t1); LGK(0); PRIO1; MFMA_Q(0,1); PRIO0; SCHED0;
        SBAR; READ_A(hA0,1); SCHED0; LGK(0);
        PRIO1; MFMA_Q(1,0); PRIO0; SCHED0; VM(0); SCHED0;   // drain: buf1 fully landed
        SBAR; READ_B(hB1,0); SCHED0; PRIO1; MFMA_Q(1,1); PRIO0; SCHED0;
        SBAR; READ_A(hA1,0); SCHED0; READ_B(hB1,1); SCHED0;
        LGK(4); PRIO1; MFMA_Q(0,0); PRIO0; SCHED0;
        SBAR; LGK(0); PRIO1; MFMA_Q(0,1); PRIO0; SCHED0;
        SBAR; READ_A(hA1,1); SCHED0; LGK(0); PRIO1; MFMA_Q(1,0); PRIO0; SCHED0;
        SBAR; PRIO1; MFMA_Q(1,1); PRIO0; SCHED0;
    }

    // ---------------- epilogue ----------------
    const int fr = lane & 15, fq = lane >> 4;
    const int rbase = m0 + wm * 128, cbase = n0 + wn * 64;

    if (EPI == 0) {
        const int wsel = n0 >> 10;          // 0=G, 1=V (block-uniform)
        if (wsel == 0) {
            short* dst = (short*)o0;        // G row-major [16384][1024]
            #pragma unroll
            for (int mi = 0; mi < 8; ++mi)
                #pragma unroll
                for (int ni = 0; ni < 4; ++ni)
                    #pragma unroll
                    for (int r = 0; r < 4; ++r) {
                        int row = rbase + mi * 16 + fq * 4 + r;
                        int col = cbase + ni * 16 + fr;
                        dst[(long)row * HD + col] = f2bf(acc[mi][ni][r]);
                    }
        } else {
            short* Vt = (short*)o2;         // [b][d][t]
            #pragma unroll
            for (int mi = 0; mi < 8; ++mi)
                #pragma unroll
                for (int ni = 0; ni < 4; ++ni) {
                    int col  = (cbase + ni * 16 + fr) & 1023;
                    int row0 = rbase + mi * 16 + fq * 4;
                    int b = row0 >> 11, t = row0 & 2047;
                    short4v v;
                    #pragma unroll
                    for (int r = 0; r < 4; ++r) v[r] = f2bf(acc[mi][ni][r]);
                    *(short4v*)&Vt[((long)b * HD + col) * T + t] = v;
                }
        }
    } else if (EPI == 1) {
        short* S = (short*)o0 + (long)bz * T * T;
        #pragma unroll
        for (int mi = 0; mi < 8; ++mi)
            #pragma unroll
            for (int ni = 0; ni < 4; ++ni)
                #pragma unroll
                for (int r = 0; r < 4; ++r) {
                    int i = rbase + mi * 16 + fq * 4 + r;
                    int j = cbase + ni * 16 + fr;
                    bool keep = (i - j <= 256) && (j - i <= 255);
                    S[(long)i * T + j] = f2bf(keep ? acc[mi][ni][r] * (1.f/32.f) : 0.f);
                }
    } else if (EPI == 2) {
        float* out = (float*)o0;
        #pragma unroll
        for (int mi = 0; mi < 8; ++mi)
            #pragma unroll
            for (int r = 0; r < 4; ++r) {
                int i = rbase + mi * 16 + fq * 4 + r;
                float ci = Crow[bz * T + i];
                #pragma unroll
                for (int ni = 0; ni < 4; ++ni) {
                    int col = cbase + ni * 16 + fr;
                    out[((long)bz * T + i) * HD + col] = acc[mi][ni][r] + ci * Vsum[bz * HD + col];
                }
            }
    } else {
        float* dst = (float*)o0 + (long)blockIdx.z * HD * HD;   // fp32 partial slice
        #pragma unroll
        for (int mi = 0; mi < 8; ++mi)
            #pragma unroll
            for (int ni = 0; ni < 4; ++ni)
                #pragma unroll
                for (int r = 0; r < 4; ++r) {
                    int row = rbase + mi * 16 + fq * 4 + r;
                    int col = cbase + ni * 16 + fr;
                    dst[(long)row * HD + col] = acc[mi][ni][r];
                }
    }
}

// ---------- band softmax: in place P' = a - c; Crow[i] = c ----------
__global__ __launch_bounds__(256)
void softmax_band(short* __restrict__ S, float* __restrict__ Crow) {
    const int T = 2048;
    int wid = (int)blockIdx.x * 4 + (threadIdx.x >> 6);
    int lane = threadIdx.x & 63;
    int b = wid >> 11, t = wid & 2047;
    int mb = t >> 7;
    int tlo = max(mb - 2, 0) * 128;
    int thi = min(mb + 2, 15) * 128 + 128;
    int nvec = (thi - tlo) >> 3;                   // 48..80
    short* row = S + ((long)b * T + t) * T + tlo;

    bool h0 = lane < nvec;
    bool h1 = lane + 64 < nvec;
    bf16x8 v0, v1;
    float f0[8], f1[8];
    float m = 0.f;                                  // masked zeros always exist
    if (h0) {
        v0 = *(const bf16x8*)&row[lane * 8];
        #pragma unroll
        for (int j = 0; j < 8; ++j) { f0[j] = bf2f(v0[j]); m = fmaxf(m, f0[j]); }
    }
    if (h1) {
        v1 = *(const bf16x8*)&row[(lane + 64) * 8];
        #pragma unroll
        for (int j = 0; j < 8; ++j) { f1[j] = bf2f(v1[j]); m = fmaxf(m, f1[j]); }
    }
    #pragma unroll
    for (int o = 32; o; o >>= 1) m = fmaxf(m, __shfl_xor(m, o));

    float e0[8], e1[8];
    float sum = 0.f;
    if (h0) {
        #pragma unroll
        for (int j = 0; j < 8; ++j) { e0[j] = __expf(f0[j] - m); sum += e0[j]; }
    }
    if (h1) {
        #pragma unroll
        for (int j = 0; j < 8; ++j) { e1[j] = __expf(f1[j] - m); sum += e1[j]; }
    }
    #pragma unroll
    for (int o = 32; o; o >>= 1) sum += __shfl_xor(sum, o);
    float em = __expf(-m);
    sum += (float)(2048 - nvec * 8) * em;
    float inv = 1.f / sum;
    float c = em * inv;

    if (h0) {
        #pragma unroll
        for (int j = 0; j < 8; ++j) v0[j] = f2bf(e0[j] * inv - c);
        *(bf16x8*)&row[lane * 8] = v0;
    }
    if (h1) {
        #pragma unroll
        for (int j = 0; j < 8; ++j) v1[j] = f2bf(e1[j] * inv - c);
        *(bf16x8*)&row[(lane + 64) * 8] = v1;
    }
    if (lane == 0) Crow[wid] = c;
}

// ---------- Vsum[b][d] = sum_t Vt[b][d][t] ----------
__global__ __launch_bounds__(256)
void vsum_rows(const short* __restrict__ Vt, float* __restrict__ Vsum) {
    int rowid = (int)blockIdx.x * 4 + (threadIdx.x >> 6);
    int lane = threadIdx.x & 63;
    const short* r = Vt + (long)rowid * 2048;
    float s = 0.f;
    #pragma unroll
    for (int v = 0; v < 4; ++v) {
        bf16x8 x = *(const bf16x8*)&r[(lane + v * 64) * 8];
        #pragma unroll
        for (int j = 0; j < 8; ++j) s += bf2f(x[j]);
    }
    #pragma unroll
    for (int o = 32; o; o >>= 1) s += __shfl_xor(s, o);
    if (lane == 0) Vsum[rowid] = s;
}

// ---------- launch ----------
extern "C" void kernel_launch(void* const* d_in, const int* in_sizes, int n_in,
                              void* d_out, int out_size, void* d_ws, size_t ws_size,
                              hipStream_t stream) {
    const int B = 8, T = 2048, H = 1024, D = 1024;
    const long MT = (long)B * T;  // 16384

    const float* X  = (const float*)d_in[0];
    const float* WQ = (const float*)d_in[1];
    const float* WK = (const float*)d_in[2];
    const float* WV = (const float*)d_in[3];
    float* out = (float*)d_out;

    char* ws = (char*)d_ws;
    size_t off = 0;
    auto alloc = [&](size_t bytes) {
        char* p = ws + off;
        off += (bytes + 255) & ~(size_t)255;
        return p;
    };
    short* Xb    = (short*)alloc(MT * H * 2);          // 33.5 MB
    short* WQb   = (short*)alloc((long)H * D * 2);     //  2 MB (row-major bf16)
    short* WKb   = (short*)alloc((long)H * D * 2);     //  2 MB
    short* Bfuse = (short*)alloc(2L * D * H * 2);      //  4 MB: [Mt | WVt] contiguous
    short* MTb   = Bfuse;                              //  Mt = WK*WQ^T  [1024][1024]
    short* WVt   = Bfuse + (long)D * H;                //  WV^T [1024][1024]
    float* Mpart = (float*)alloc(4L * D * H * 4);      // 16 MB fp32 split-K partials
    short* Gb    = (short*)alloc(MT * D * 2);          // 33.5 MB  G = X*M
    short* Vt    = (short*)alloc((long)B * D * T * 2); // 33.5 MB  [b][d][t]
    short* S     = (short*)alloc((long)B * T * T * 2); // 67.1 MB  (band tiles only)
    float* Crow  = (float*)alloc(MT * 4);              // 64 KB
    float* Vsum  = (float*)alloc((long)B * D * 4);     // 32 KB
    if (off > ws_size) return;

    // 1) bf16 conversions
    cvt_f32_bf16<<<(int)(MT * H / 2048), 256, 0, stream>>>(X, Xb);
    cvt_f32_bf16<<<512, 256, 0, stream>>>(WQ, WQb);
    cvt_f32_bf16<<<512, 256, 0, stream>>>(WK, WKb);
    transpose_w<<<dim3(32, 32), 256, 0, stream>>>(WV, WVt);

    // 2) Mt = WK * WQ^T, split-K over 4 slices (64 blocks) + reduce to bf16
    gemm256<3><<<dim3(4, 4, 4), 512, 0, stream>>>(WKb, WQb, Mpart, nullptr, nullptr, nullptr, nullptr);
    reduce_mt<<<512, 256, 0, stream>>>(Mpart, MTb);

    // 3) fused [G | V] projection: A = Xb, B = [Mt | WVt]  (N = 2048, 2 rounds)
    gemm256<0><<<dim3(8, 64, 1), 512, 0, stream>>>(Xb, Bfuse, Gb, nullptr, Vt, nullptr, nullptr);

    // 4) V column sums (rank-1 masked correction)
    vsum_rows<<<(int)(B * D / 4), 256, 0, stream>>>(Vt, Vsum);

    // 5) band scores: S = (G X^T)/32, B operand is Xb directly (K proj eliminated)
    gemm256<1><<<dim3(3, 8, B), 512, 0, stream>>>(Gb, Xb, S, nullptr, nullptr, nullptr, nullptr);

    // 6) band softmax -> P' = a - c in place, c per row
    softmax_band<<<(int)(MT / 4), 256, 0, stream>>>(S, Crow);

    // 7) band PV + rank-1 correction
    gemm256<2><<<dim3(4, 8, B), 512, 0, stream>>>(S, Vt, out, nullptr, nullptr, Crow, Vsum);
}